// Round 2
// baseline (523.413 us; speedup 1.0000x reference)
//
#include <hip/hip_runtime.h>
#include <hip/hip_bf16.h>
#include <stdint.h>

// Problem constants (fixed shapes)
#define BB 16
#define HH 32
#define WW 64
#define CC 768
#define W2C 33                   // WW/2+1
#define ROWW (2*CC)              // 1536 = NB*2*BS, spectral row layout (nb, re/im, bs)

typedef __bf16 bf16x8 __attribute__((ext_vector_type(8)));
typedef float f32x4 __attribute__((ext_vector_type(4)));

__device__ __forceinline__ unsigned short f2bf(float f) {
  __hip_bfloat16 h = __float2bfloat16(f);
  return __builtin_bit_cast(unsigned short, h);
}
__device__ __forceinline__ float bf2f(unsigned short u) {
  union { unsigned int i; float f; } x;
  x.i = ((unsigned int)u) << 16;
  return x.f;
}

// async global->LDS, 16B per lane (guide Sec 5: the m93->m97 2x step)
__device__ __forceinline__ void g2l16(const void* g, void* l) {
  __builtin_amdgcn_global_load_lds((const __attribute__((address_space(1))) unsigned int*)g,
                                   (__attribute__((address_space(3))) unsigned int*)l,
                                   16, 0, 0);
}

// compile-time bit reversal (folds after full unroll -> keeps v[] in VGPRs)
__device__ __host__ constexpr int brevc(int x, int bits) {
  int r = 0;
  for (int i = 0; i < bits; ++i) r |= ((x >> i) & 1) << (bits - 1 - i);
  return r;
}

// ---------------- radix-2 DIF FFT in registers ----------------
template<int N, bool INV>
__device__ __forceinline__ void fft_reg(float2 (&v)[N], const float2* __restrict__ tw) {
  constexpr int LOG2N = (N == 64) ? 6 : 5;
#pragma unroll
  for (int s = 0; s < LOG2N; ++s) {
    const int len = N >> s;
    const int half = len >> 1;
    const int tstep = 64 / len;
#pragma unroll
    for (int i = 0; i < N; i += len) {
#pragma unroll
      for (int j = 0; j < half; ++j) {
        float2 u = v[i + j];
        float2 t = v[i + j + half];
        float sr = u.x + t.x, si = u.y + t.y;
        float dr = u.x - t.x, di = u.y - t.y;
        float2 w = tw[j * tstep];
        float wr = w.x;
        float wi = INV ? -w.y : w.y;
        v[i + j] = make_float2(sr, si);
        v[i + j + half] = make_float2(dr * wr - di * wi, dr * wi + di * wr);
      }
    }
  }
}

#define TW_INIT()                                                            \
  __shared__ float2 tw[64];                                                  \
  if (threadIdx.x < 64) {                                                    \
    float ang = (float)threadIdx.x * 0.09817477042468103f; /* 2pi/64 */      \
    tw[threadIdx.x] = make_float2(cosf(ang), -sinf(ang));                    \
  }                                                                          \
  __syncthreads();

// ---------------- forward FFT pass A: real DFT along W (64 -> 33 cplx) ----------------
// Also emits the bf16 copy of x (for the bias GEMM) for free while reading x.
__global__ __launch_bounds__(256) void fft_fwd_w(const float* __restrict__ x,
                                                 ushort2* __restrict__ yw,
                                                 unsigned short* __restrict__ xb) {
  TW_INIT();
  const int bh = blockIdx.x;
  const int c = blockIdx.y * 256 + threadIdx.x;
  const float* xp = x + (size_t)bh * (WW * CC) + c;
  unsigned short* xbp = xb + (size_t)bh * (WW * CC) + c;
  float2 v[64];
#pragma unroll
  for (int w = 0; w < 64; ++w) {
    float f = xp[(size_t)w * CC];
    v[w] = make_float2(f, 0.f);
    xbp[(size_t)w * CC] = f2bf(f);
  }
  fft_reg<64, false>(v, tw);
  ushort2* yp = yw + (size_t)bh * (W2C * CC) + c;
#pragma unroll
  for (int k = 0; k <= 32; ++k) {
    float2 z = v[brevc(k, 6)];
    yp[(size_t)k * CC] = make_ushort2(f2bf(z.x), f2bf(z.y));
  }
}

// ---------------- forward FFT pass B: complex DFT along H (32), scale, write GEMM layout ---
__global__ __launch_bounds__(256) void fft_fwd_h(const ushort2* __restrict__ yw,
                                                 unsigned short* __restrict__ xf) {
  TW_INIT();
  const int bk = blockIdx.x;
  const int b = bk / W2C, kw = bk - b * W2C;
  const int c = blockIdx.y * 256 + threadIdx.x;
  const ushort2* yp = yw + ((size_t)b * HH * W2C + kw) * CC + c;
  float2 v[32];
#pragma unroll
  for (int h = 0; h < 32; ++h) {
    ushort2 u = yp[(size_t)h * (W2C * CC)];
    v[h] = make_float2(bf2f(u.x), bf2f(u.y));
  }
  fft_reg<32, false>(v, tw);
  const int nb = c / 192, cc = c - nb * 192;
  unsigned short* xp = xf + (size_t)nb * 384 + cc;
  const float s = 0.022097086912079608f; // 1/sqrt(2048)  (ortho fwd)
#pragma unroll
  for (int kh = 0; kh < 32; ++kh) {
    float2 z = v[brevc(kh, 5)];
    size_t m = ((size_t)b * HH + kh) * W2C + kw;
    xp[m * ROWW] = f2bf(z.x * s);
    xp[m * ROWW + 192] = f2bf(z.y * s);
  }
}

// ---------------- inverse FFT pass A: complex inverse DFT along H ----------------
__global__ __launch_bounds__(256) void fft_inv_h(const unsigned short* __restrict__ r2,
                                                 ushort2* __restrict__ g) {
  TW_INIT();
  const int bk = blockIdx.x;
  const int b = bk / W2C, kw = bk - b * W2C;
  const int c = blockIdx.y * 256 + threadIdx.x;
  const int nb = c / 192, cc = c - nb * 192;
  const unsigned short* rp = r2 + (size_t)nb * 384 + cc;
  float2 v[32];
#pragma unroll
  for (int kh = 0; kh < 32; ++kh) {
    size_t m = ((size_t)b * HH + kh) * W2C + kw;
    v[kh] = make_float2(bf2f(rp[m * ROWW]), bf2f(rp[m * ROWW + 192]));
  }
  fft_reg<32, true>(v, tw);
  ushort2* gp = g + ((size_t)b * HH * W2C + kw) * CC + c;
#pragma unroll
  for (int h = 0; h < 32; ++h) {
    float2 z = v[brevc(h, 5)];
    gp[(size_t)h * (W2C * CC)] = make_ushort2(f2bf(z.x), f2bf(z.y));
  }
}

// ---------------- inverse FFT pass B: irfft along W (33 -> 64 real) + bias, pure write ----
__global__ __launch_bounds__(256) void fft_inv_w(const ushort2* __restrict__ g,
                                                 const unsigned short* __restrict__ biasb,
                                                 float* __restrict__ out) {
  TW_INIT();
  const int bh = blockIdx.x;
  const int c = blockIdx.y * 256 + threadIdx.x;
  const ushort2* gp = g + (size_t)bh * (W2C * CC) + c;
  float2 v[64];
  {
    ushort2 u0 = gp[0];
    v[0] = make_float2(bf2f(u0.x), 0.f);
    ushort2 u32 = gp[(size_t)32 * CC];
    v[32] = make_float2(bf2f(u32.x), 0.f);
  }
#pragma unroll
  for (int k = 1; k < 32; ++k) {
    ushort2 u = gp[(size_t)k * CC];
    float2 z = make_float2(bf2f(u.x), bf2f(u.y));
    v[k] = z;
    v[64 - k] = make_float2(z.x, -z.y); // hermitian extension
  }
  fft_reg<64, true>(v, tw);
  float* op = out + (size_t)bh * (WW * CC) + c;
  const unsigned short* bp = biasb + (size_t)bh * (WW * CC) + c;
  const float s = 0.022097086912079608f; // 1/sqrt(2048)  (ortho inv)
#pragma unroll
  for (int w = 0; w < 64; ++w) {
    float2 z = v[brevc(w, 6)];
    op[(size_t)w * CC] = z.x * s + bf2f(bp[(size_t)w * CC]);
  }
}

// ---------------- bf16 MFMA GEMM (m97 structure + XOR bank swizzle) ----------------
// out = A * B^T + bias.  A: (M x K) bf16 row-major + z*aZ; Bw: (N x K) n-major + z*bZ.
// exact tiles only: M%128==0, (N per z)%128==0, K%32==0.
// LDS swizzle: 16B chunk c of row r stored at slot (c ^ ((r>>1)&3)); makes every
// ds_read_b128 a 2-way bank pattern (free, m136) instead of 8-way.
template<bool RELU, bool OBF>
__global__ __launch_bounds__(256) void gemm_bt(
    const unsigned short* __restrict__ A, int lda, int aZ,
    const unsigned short* __restrict__ Bw, int K, int bZ,
    const float* __restrict__ bias, int biasZ,
    void* __restrict__ outp, int ldo, int oZ) {
  __shared__ __align__(16) unsigned short As[128 * 32];
  __shared__ __align__(16) unsigned short Bs[128 * 32];
  const int t = threadIdx.x;
  const int z = blockIdx.z;
  const size_t m0 = (size_t)blockIdx.x * 128;
  const int n0 = blockIdx.y * 128;
  const unsigned short* Ap = A + m0 * lda + (size_t)z * aZ;
  const unsigned short* Bp = Bw + (size_t)n0 * K + (size_t)z * bZ;
  const int lane = t & 63, wave = t >> 6;
  const int lr = lane & 15, quad = lane >> 4;
  const int wm = (wave >> 1) * 64, wn = (wave & 1) * 64;
  const int row = t >> 2;                     // 0..63
  const int sl = t & 3;                       // 16B slot within row
  const int kb = (sl ^ ((row >> 1) & 3)) * 8; // swizzled global k-chunk
  const int swzf = (lr >> 1) & 3;             // fragment-read swizzle
  f32x4 acc[4][4] = {};
  for (int k0 = 0; k0 < K; k0 += 32) {
    const unsigned short* ga = Ap + (size_t)row * lda + (k0 + kb);
    g2l16(ga, &As[row * 32 + sl * 8]);
    g2l16(ga + (size_t)64 * lda, &As[(row + 64) * 32 + sl * 8]);
    const unsigned short* gb = Bp + (size_t)row * K + (k0 + kb);
    g2l16(gb, &Bs[row * 32 + sl * 8]);
    g2l16(gb + (size_t)64 * K, &Bs[(row + 64) * 32 + sl * 8]);
    __syncthreads(); // compiler emits vmcnt(0) drain for global_load_lds
    bf16x8 af[4], bfr[4];
#pragma unroll
    for (int mi = 0; mi < 4; ++mi)
      af[mi] = *(const bf16x8*)&As[(wm + mi * 16 + lr) * 32 + ((quad ^ swzf) * 8)];
#pragma unroll
    for (int ni = 0; ni < 4; ++ni)
      bfr[ni] = *(const bf16x8*)&Bs[(wn + ni * 16 + lr) * 32 + ((quad ^ swzf) * 8)];
#pragma unroll
    for (int mi = 0; mi < 4; ++mi)
#pragma unroll
      for (int ni = 0; ni < 4; ++ni)
        acc[mi][ni] = __builtin_amdgcn_mfma_f32_16x16x32_bf16(af[mi], bfr[ni], acc[mi][ni], 0, 0, 0);
    __syncthreads();
  }
#pragma unroll
  for (int mi = 0; mi < 4; ++mi) {
    const size_t mrow = m0 + wm + mi * 16 + quad * 4;
#pragma unroll
    for (int ni = 0; ni < 4; ++ni) {
      const int ncol = n0 + wn + ni * 16 + lr;
      const float bv = bias[z * biasZ + ncol];
#pragma unroll
      for (int r = 0; r < 4; ++r) {
        float vv = acc[mi][ni][r] + bv;
        if (RELU) vv = fmaxf(vv, 0.f);
        const size_t off = (mrow + r) * (size_t)ldo + (size_t)z * oZ + ncol;
        if (OBF) ((unsigned short*)outp)[off] = f2bf(vv);
        else ((float*)outp)[off] = vv;
      }
    }
  }
}

// ---------------- prep kernels ----------------
__global__ __launch_bounds__(256) void cvt_bf16(const float* __restrict__ in,
                                                unsigned short* __restrict__ outp) {
  const size_t i = ((size_t)blockIdx.x * 256 + threadIdx.x) * 4;
  float4 v = *(const float4*)(in + i);
  ushort4 o = make_ushort4(f2bf(v.x), f2bf(v.y), f2bf(v.z), f2bf(v.w));
  *(ushort4*)(outp + i) = o;
}

// Combined layer-1 weights, stored n-major (nb, n, k), k,n in [0,384)
__global__ __launch_bounds__(256) void build_w1(const float* __restrict__ w1,
                                                const float* __restrict__ b1,
                                                unsigned short* __restrict__ w1t,
                                                float* __restrict__ bias1) {
  const int idx = blockIdx.x * 256 + threadIdx.x;
  const int nb = idx / (384 * 384);
  const int rem = idx - nb * (384 * 384);
  const int n = rem / 384, k = rem - (rem / 384) * 384;
  const bool khi = k >= 192, nhi = n >= 192;
  const int kk = khi ? k - 192 : k, nn = nhi ? n - 192 : n;
  float val;
  if (!khi && !nhi)      val =  w1[((0 * 4 + nb) * 192 + kk) * 192 + nn];
  else if (khi && !nhi)  val = -w1[((1 * 4 + nb) * 192 + kk) * 192 + nn];
  else if (!khi && nhi)  val =  w1[((1 * 4 + nb) * 192 + kk) * 192 + nn];
  else                   val =  w1[((0 * 4 + nb) * 192 + kk) * 192 + nn];
  w1t[((size_t)nb * 384 + n) * 384 + k] = f2bf(val);
  if (k == 0)
    bias1[nb * 384 + n] = nhi ? b1[(1 * 4 + nb) * 192 + nn] : b1[(0 * 4 + nb) * 192 + nn];
}

// Combined layer-2 weights (folds the in-place r2->i2 dependency).
__global__ __launch_bounds__(256) void build_w2(const float* __restrict__ w2,
                                                const float* __restrict__ b2,
                                                unsigned short* __restrict__ w2t,
                                                float* __restrict__ bias2) {
  const int idx = blockIdx.x * 256 + threadIdx.x;
  const int nb = idx / (384 * 384);
  const int rem = idx - nb * (384 * 384);
  const int n = rem / 384, k = rem - (rem / 384) * 384;
  const bool khi = k >= 192, nhi = n >= 192;
  const int kk = khi ? k - 192 : k, nn = nhi ? n - 192 : n;
  float val;
  if (!khi && !nhi) {
    val = w2[((0 * 4 + nb) * 192 + kk) * 192 + nn];
  } else if (khi && !nhi) {
    val = -w2[((1 * 4 + nb) * 192 + kk) * 192 + nn];
  } else if (!khi && nhi) {
    float s = 0.f;
    for (int d = 0; d < 192; ++d)
      s += w2[((0 * 4 + nb) * 192 + kk) * 192 + d] * w2[((1 * 4 + nb) * 192 + d) * 192 + nn];
    val = s;
  } else {
    float s = 0.f;
    for (int d = 0; d < 192; ++d)
      s += w2[((1 * 4 + nb) * 192 + kk) * 192 + d] * w2[((1 * 4 + nb) * 192 + d) * 192 + nn];
    val = w2[((0 * 4 + nb) * 192 + kk) * 192 + nn] - s;
  }
  w2t[((size_t)nb * 384 + n) * 384 + k] = f2bf(val);
  if (k == 0) {
    float bv;
    if (!nhi) {
      bv = b2[(0 * 4 + nb) * 192 + nn];
    } else {
      float s = 0.f;
      for (int d = 0; d < 192; ++d)
        s += b2[(0 * 4 + nb) * 192 + d] * w2[((1 * 4 + nb) * 192 + d) * 192 + nn];
      bv = b2[(1 * 4 + nb) * 192 + nn] + s;
    }
    bias2[nb * 384 + n] = bv;
  }
}

// ---------------- launcher ----------------
extern "C" void kernel_launch(void* const* d_in, const int* in_sizes, int n_in,
                              void* d_out, int out_size, void* d_ws, size_t ws_size,
                              hipStream_t stream) {
  (void)in_sizes; (void)n_in; (void)out_size; (void)ws_size;
  const float* x  = (const float*)d_in[0];
  const float* w1 = (const float*)d_in[1];
  const float* b1 = (const float*)d_in[2];
  const float* w2 = (const float*)d_in[3];
  const float* b2 = (const float*)d_in[4];
  const float* bw = (const float*)d_in[5];
  const float* bb = (const float*)d_in[6];
  float* out = (float*)d_out;

  // workspace (aliased lifetimes):
  //   buf1: Yw -> R1I1 -> G
  //   buf2: x_bf16 -> R2I2
  //   buf3: xf -> bias_bf16
  char* p = (char*)d_ws;
  unsigned short* buf1 = (unsigned short*)p; p += 51904512;
  unsigned short* buf2 = (unsigned short*)p; p += 51904512;
  unsigned short* buf3 = (unsigned short*)p; p += 51904512;
  unsigned short* bwb  = (unsigned short*)p; p += 1179648;
  unsigned short* w1t  = (unsigned short*)p; p += 1179648;
  unsigned short* w2t  = (unsigned short*)p; p += 1179648;
  float* bias1 = (float*)p; p += 6144;
  float* bias2 = (float*)p; p += 6144;

  // prep (small)
  cvt_bf16<<<589824 / 1024, 256, 0, stream>>>(bw, bwb);
  build_w1<<<589824 / 256, 256, 0, stream>>>(w1, b1, w1t, bias1);
  build_w2<<<589824 / 256, 256, 0, stream>>>(w2, b2, w2t, bias2);
  // forward FFT (pass A also emits x_bf16 into buf2)
  fft_fwd_w<<<dim3(BB * HH, 3), 256, 0, stream>>>(x, (ushort2*)buf1, buf2);
  fft_fwd_h<<<dim3(BB * W2C, 3), 256, 0, stream>>>((const ushort2*)buf1, buf3);
  // spectral layer 1 (consumes buf3=xf, frees it)
  gemm_bt<true, true><<<dim3(132, 3, 4), 256, 0, stream>>>(
      buf3, ROWW, 384, w1t, 384, 384 * 384, bias1, 384, buf1, ROWW, 384);
  // bias path GEMM -> bf16 into buf3 (M=32768, N=768, K=768)
  gemm_bt<false, true><<<dim3(256, 6, 1), 256, 0, stream>>>(
      buf2, 768, 0, bwb, 768, 0, bb, 0, buf3, 768, 0);
  // spectral layer 2
  gemm_bt<false, true><<<dim3(132, 3, 4), 256, 0, stream>>>(
      buf1, ROWW, 384, w2t, 384, 384 * 384, bias2, 384, buf2, ROWW, 384);
  // inverse FFT (+ bias, pure write of out)
  fft_inv_h<<<dim3(BB * W2C, 3), 256, 0, stream>>>(buf2, (ushort2*)buf1);
  fft_inv_w<<<dim3(BB * HH, 3), 256, 0, stream>>>((const ushort2*)buf1, buf3, out);
}

// Round 3
// 487.991 us; speedup vs baseline: 1.0726x; 1.0726x over previous
//
#include <hip/hip_runtime.h>
#include <hip/hip_bf16.h>
#include <stdint.h>

// Problem constants (fixed shapes)
#define BB 16
#define HH 32
#define WW 64
#define CC 768
#define W2C 33                   // WW/2+1
#define ROWW (2*CC)              // 1536 = NB*2*BS, spectral row layout (nb, re/im, bs)

typedef __bf16 bf16x8 __attribute__((ext_vector_type(8)));
typedef float f32x4 __attribute__((ext_vector_type(4)));

__device__ __forceinline__ unsigned short f2bf(float f) {
  __hip_bfloat16 h = __float2bfloat16(f);
  return __builtin_bit_cast(unsigned short, h);
}
__device__ __forceinline__ float bf2f(unsigned short u) {
  union { unsigned int i; float f; } x;
  x.i = ((unsigned int)u) << 16;
  return x.f;
}

// async global->LDS, 16B per lane
__device__ __forceinline__ void g2l16(const void* g, void* l) {
  __builtin_amdgcn_global_load_lds((const __attribute__((address_space(1))) unsigned int*)g,
                                   (__attribute__((address_space(3))) unsigned int*)l,
                                   16, 0, 0);
}

// compile-time bit reversal (folds after full unroll)
__device__ __host__ constexpr int brevc(int x, int bits) {
  int r = 0;
  for (int i = 0; i < bits; ++i) r |= ((x >> i) & 1) << (bits - 1 - i);
  return r;
}

// ---------------- radix-2 DIF FFT in registers (32-point only now) ----------------
template<int N, bool INV>
__device__ __forceinline__ void fft_reg(float2 (&v)[N], const float2* __restrict__ tw) {
  constexpr int LOG2N = (N == 64) ? 6 : 5;
#pragma unroll
  for (int s = 0; s < LOG2N; ++s) {
    const int len = N >> s;
    const int half = len >> 1;
    const int tstep = 64 / len;
#pragma unroll
    for (int i = 0; i < N; i += len) {
#pragma unroll
      for (int j = 0; j < half; ++j) {
        float2 u = v[i + j];
        float2 t = v[i + j + half];
        float sr = u.x + t.x, si = u.y + t.y;
        float dr = u.x - t.x, di = u.y - t.y;
        float2 w = tw[j * tstep];
        float wr = w.x;
        float wi = INV ? -w.y : w.y;
        v[i + j] = make_float2(sr, si);
        v[i + j + half] = make_float2(dr * wr - di * wi, dr * wi + di * wr);
      }
    }
  }
}

#define TW_INIT()                                                            \
  __shared__ float2 tw[64];                                                  \
  if (threadIdx.x < 64) {                                                    \
    float ang = (float)threadIdx.x * 0.09817477042468103f; /* 2pi/64 */      \
    tw[threadIdx.x] = make_float2(cosf(ang), -sinf(ang));                    \
  }                                                                          \
  __syncthreads();

// ---------------- forward pass A: rfft64 along W via packed 32-pt complex FFT ----------
// z[n] = x[2n] + i x[2n+1]; Z = FFT32(z); X[k] = E[k] + W64^k O[k].
// Also emits bf16 copy of x for the bias GEMM.
__global__ __launch_bounds__(256) void fft_fwd_w(const float* __restrict__ x,
                                                 ushort2* __restrict__ yw,
                                                 unsigned short* __restrict__ xb) {
  TW_INIT();
  const int bh = blockIdx.x;
  const int c = blockIdx.y * 256 + threadIdx.x;
  const float* xp = x + (size_t)bh * (WW * CC) + c;
  unsigned short* xbp = xb + (size_t)bh * (WW * CC) + c;
  float2 v[32];
#pragma unroll
  for (int n = 0; n < 32; ++n) {
    float a = xp[(size_t)(2 * n) * CC];
    float b = xp[(size_t)(2 * n + 1) * CC];
    xbp[(size_t)(2 * n) * CC] = f2bf(a);
    xbp[(size_t)(2 * n + 1) * CC] = f2bf(b);
    v[n] = make_float2(a, b);
  }
  fft_reg<32, false>(v, tw);
  ushort2* yp = yw + (size_t)bh * (W2C * CC) + c;
  {
    float2 Z0 = v[0];
    yp[0] = make_ushort2(f2bf(Z0.x + Z0.y), f2bf(0.f));
    yp[(size_t)32 * CC] = make_ushort2(f2bf(Z0.x - Z0.y), f2bf(0.f));
  }
#pragma unroll
  for (int k = 1; k < 32; ++k) {
    float2 Zk = v[brevc(k, 5)];
    float2 Zm = v[brevc(32 - k, 5)];
    float Er = 0.5f * (Zk.x + Zm.x), Ei = 0.5f * (Zk.y - Zm.y);
    float Odr = 0.5f * (Zk.y + Zm.y), Odi = -0.5f * (Zk.x - Zm.x);
    float2 w = tw[k];                       // W64^k = (cos, -sin)
    float Xr = Er + w.x * Odr - w.y * Odi;
    float Xi = Ei + w.x * Odi + w.y * Odr;
    yp[(size_t)k * CC] = make_ushort2(f2bf(Xr), f2bf(Xi));
  }
}

// ---------------- forward pass B: complex DFT along H (32), scale, write GEMM layout ---
__global__ __launch_bounds__(256) void fft_fwd_h(const ushort2* __restrict__ yw,
                                                 unsigned short* __restrict__ xf) {
  TW_INIT();
  const int bk = blockIdx.x;
  const int b = bk / W2C, kw = bk - b * W2C;
  const int c = blockIdx.y * 256 + threadIdx.x;
  const ushort2* yp = yw + ((size_t)b * HH * W2C + kw) * CC + c;
  float2 v[32];
#pragma unroll
  for (int h = 0; h < 32; ++h) {
    ushort2 u = yp[(size_t)h * (W2C * CC)];
    v[h] = make_float2(bf2f(u.x), bf2f(u.y));
  }
  fft_reg<32, false>(v, tw);
  const int nb = c / 192, cc = c - nb * 192;
  unsigned short* xp = xf + (size_t)nb * 384 + cc;
  const float s = 0.022097086912079608f; // 1/sqrt(2048)  (ortho fwd)
#pragma unroll
  for (int kh = 0; kh < 32; ++kh) {
    float2 z = v[brevc(kh, 5)];
    size_t m = ((size_t)b * HH + kh) * W2C + kw;
    xp[m * ROWW] = f2bf(z.x * s);
    xp[m * ROWW + 192] = f2bf(z.y * s);
  }
}

// ---------------- inverse pass A: complex inverse DFT along H ----------------
__global__ __launch_bounds__(256) void fft_inv_h(const unsigned short* __restrict__ r2,
                                                 ushort2* __restrict__ g) {
  TW_INIT();
  const int bk = blockIdx.x;
  const int b = bk / W2C, kw = bk - b * W2C;
  const int c = blockIdx.y * 256 + threadIdx.x;
  const int nb = c / 192, cc = c - nb * 192;
  const unsigned short* rp = r2 + (size_t)nb * 384 + cc;
  float2 v[32];
#pragma unroll
  for (int kh = 0; kh < 32; ++kh) {
    size_t m = ((size_t)b * HH + kh) * W2C + kw;
    v[kh] = make_float2(bf2f(rp[m * ROWW]), bf2f(rp[m * ROWW + 192]));
  }
  fft_reg<32, true>(v, tw);
  ushort2* gp = g + ((size_t)b * HH * W2C + kw) * CC + c;
#pragma unroll
  for (int h = 0; h < 32; ++h) {
    float2 z = v[brevc(h, 5)];
    gp[(size_t)h * (W2C * CC)] = make_ushort2(f2bf(z.x), f2bf(z.y));
  }
}

// ---------------- inverse pass B: irfft64 along W via packed 32-pt inverse FFT --------
// A[k]=(X[k]+conj(X[32-k]))/2, B[k]=W64^{-k}(X[k]-conj(X[32-k]))/2, Z=A+iB,
// z' = unnormalized IFFT32(Z) => y[2m]=2 Re z'[m], y[2m+1]=2 Im z'[m].
// imag of bins 0 and 32 ignored (pocketfft c2r). Adds bias path, pure write of out.
__global__ __launch_bounds__(256) void fft_inv_w(const ushort2* __restrict__ g,
                                                 const unsigned short* __restrict__ biasb,
                                                 float* __restrict__ out) {
  TW_INIT();
  const int bh = blockIdx.x;
  const int c = blockIdx.y * 256 + threadIdx.x;
  const ushort2* gp = g + (size_t)bh * (W2C * CC) + c;
  float2 v[32];
  {
    float X0 = bf2f(gp[0].x);
    float X32 = bf2f(gp[(size_t)32 * CC].x);
    v[0] = make_float2(0.5f * (X0 + X32), 0.5f * (X0 - X32));
  }
#pragma unroll
  for (int k = 1; k < 32; ++k) {
    ushort2 uk = gp[(size_t)k * CC];
    ushort2 um = gp[(size_t)(32 - k) * CC];
    float2 Xk = make_float2(bf2f(uk.x), bf2f(uk.y));
    float2 Xm = make_float2(bf2f(um.x), bf2f(um.y));
    float Ar = 0.5f * (Xk.x + Xm.x), Ai = 0.5f * (Xk.y - Xm.y);
    float Dr = 0.5f * (Xk.x - Xm.x), Di = 0.5f * (Xk.y + Xm.y);
    float2 w = tw[k];                       // W64^{-k} = (w.x, -w.y)
    float Br = w.x * Dr + w.y * Di;
    float Bi = w.x * Di - w.y * Dr;
    v[k] = make_float2(Ar - Bi, Ai + Br);
  }
  fft_reg<32, true>(v, tw);
  float* op = out + (size_t)bh * (WW * CC) + c;
  const unsigned short* bp = biasb + (size_t)bh * (WW * CC) + c;
  const float s2 = 0.04419417382415922f; // 2/sqrt(2048)
#pragma unroll
  for (int m = 0; m < 32; ++m) {
    float2 z = v[brevc(m, 5)];
    op[(size_t)(2 * m) * CC] = z.x * s2 + bf2f(bp[(size_t)(2 * m) * CC]);
    op[(size_t)(2 * m + 1) * CC] = z.y * s2 + bf2f(bp[(size_t)(2 * m + 1) * CC]);
  }
}

// ---------------- bf16 MFMA GEMM (m97 structure + XOR bank swizzle) ----------------
template<bool RELU, bool OBF>
__global__ __launch_bounds__(256) void gemm_bt(
    const unsigned short* __restrict__ A, int lda, int aZ,
    const unsigned short* __restrict__ Bw, int K, int bZ,
    const float* __restrict__ bias, int biasZ,
    void* __restrict__ outp, int ldo, int oZ) {
  __shared__ __align__(16) unsigned short As[128 * 32];
  __shared__ __align__(16) unsigned short Bs[128 * 32];
  const int t = threadIdx.x;
  const int z = blockIdx.z;
  const size_t m0 = (size_t)blockIdx.x * 128;
  const int n0 = blockIdx.y * 128;
  const unsigned short* Ap = A + m0 * lda + (size_t)z * aZ;
  const unsigned short* Bp = Bw + (size_t)n0 * K + (size_t)z * bZ;
  const int lane = t & 63, wave = t >> 6;
  const int lr = lane & 15, quad = lane >> 4;
  const int wm = (wave >> 1) * 64, wn = (wave & 1) * 64;
  const int row = t >> 2;                     // 0..63
  const int sl = t & 3;                       // 16B slot within row
  const int kb = (sl ^ ((row >> 1) & 3)) * 8; // swizzled global k-chunk
  const int swzf = (lr >> 1) & 3;             // fragment-read swizzle
  f32x4 acc[4][4] = {};
  for (int k0 = 0; k0 < K; k0 += 32) {
    const unsigned short* ga = Ap + (size_t)row * lda + (k0 + kb);
    g2l16(ga, &As[row * 32 + sl * 8]);
    g2l16(ga + (size_t)64 * lda, &As[(row + 64) * 32 + sl * 8]);
    const unsigned short* gb = Bp + (size_t)row * K + (k0 + kb);
    g2l16(gb, &Bs[row * 32 + sl * 8]);
    g2l16(gb + (size_t)64 * K, &Bs[(row + 64) * 32 + sl * 8]);
    __syncthreads();
    bf16x8 af[4], bfr[4];
#pragma unroll
    for (int mi = 0; mi < 4; ++mi)
      af[mi] = *(const bf16x8*)&As[(wm + mi * 16 + lr) * 32 + ((quad ^ swzf) * 8)];
#pragma unroll
    for (int ni = 0; ni < 4; ++ni)
      bfr[ni] = *(const bf16x8*)&Bs[(wn + ni * 16 + lr) * 32 + ((quad ^ swzf) * 8)];
#pragma unroll
    for (int mi = 0; mi < 4; ++mi)
#pragma unroll
      for (int ni = 0; ni < 4; ++ni)
        acc[mi][ni] = __builtin_amdgcn_mfma_f32_16x16x32_bf16(af[mi], bfr[ni], acc[mi][ni], 0, 0, 0);
    __syncthreads();
  }
#pragma unroll
  for (int mi = 0; mi < 4; ++mi) {
    const size_t mrow = m0 + wm + mi * 16 + quad * 4;
#pragma unroll
    for (int ni = 0; ni < 4; ++ni) {
      const int ncol = n0 + wn + ni * 16 + lr;
      const float bv = bias[z * biasZ + ncol];
#pragma unroll
      for (int r = 0; r < 4; ++r) {
        float vv = acc[mi][ni][r] + bv;
        if (RELU) vv = fmaxf(vv, 0.f);
        const size_t off = (mrow + r) * (size_t)ldo + (size_t)z * oZ + ncol;
        if (OBF) ((unsigned short*)outp)[off] = f2bf(vv);
        else ((float*)outp)[off] = vv;
      }
    }
  }
}

// ---------------- prep kernels ----------------
__global__ __launch_bounds__(256) void cvt_bf16(const float* __restrict__ in,
                                                unsigned short* __restrict__ outp) {
  const size_t i = ((size_t)blockIdx.x * 256 + threadIdx.x) * 4;
  float4 v = *(const float4*)(in + i);
  ushort4 o = make_ushort4(f2bf(v.x), f2bf(v.y), f2bf(v.z), f2bf(v.w));
  *(ushort4*)(outp + i) = o;
}

// Combined layer-1 weights, stored n-major (nb, n, k), k,n in [0,384)
__global__ __launch_bounds__(256) void build_w1(const float* __restrict__ w1,
                                                const float* __restrict__ b1,
                                                unsigned short* __restrict__ w1t,
                                                float* __restrict__ bias1) {
  const int idx = blockIdx.x * 256 + threadIdx.x;
  const int nb = idx / (384 * 384);
  const int rem = idx - nb * (384 * 384);
  const int n = rem / 384, k = rem - (rem / 384) * 384;
  const bool khi = k >= 192, nhi = n >= 192;
  const int kk = khi ? k - 192 : k, nn = nhi ? n - 192 : n;
  float val;
  if (!khi && !nhi)      val =  w1[((0 * 4 + nb) * 192 + kk) * 192 + nn];
  else if (khi && !nhi)  val = -w1[((1 * 4 + nb) * 192 + kk) * 192 + nn];
  else if (!khi && nhi)  val =  w1[((1 * 4 + nb) * 192 + kk) * 192 + nn];
  else                   val =  w1[((0 * 4 + nb) * 192 + kk) * 192 + nn];
  w1t[((size_t)nb * 384 + n) * 384 + k] = f2bf(val);
  if (k == 0)
    bias1[nb * 384 + n] = nhi ? b1[(1 * 4 + nb) * 192 + nn] : b1[(0 * 4 + nb) * 192 + nn];
}

// Combined layer-2 weights (folds the in-place r2->i2 dependency).
__global__ __launch_bounds__(256) void build_w2(const float* __restrict__ w2,
                                                const float* __restrict__ b2,
                                                unsigned short* __restrict__ w2t,
                                                float* __restrict__ bias2) {
  const int idx = blockIdx.x * 256 + threadIdx.x;
  const int nb = idx / (384 * 384);
  const int rem = idx - nb * (384 * 384);
  const int n = rem / 384, k = rem - (rem / 384) * 384;
  const bool khi = k >= 192, nhi = n >= 192;
  const int kk = khi ? k - 192 : k, nn = nhi ? n - 192 : n;
  float val;
  if (!khi && !nhi) {
    val = w2[((0 * 4 + nb) * 192 + kk) * 192 + nn];
  } else if (khi && !nhi) {
    val = -w2[((1 * 4 + nb) * 192 + kk) * 192 + nn];
  } else if (!khi && nhi) {
    float s = 0.f;
    for (int d = 0; d < 192; ++d)
      s += w2[((0 * 4 + nb) * 192 + kk) * 192 + d] * w2[((1 * 4 + nb) * 192 + d) * 192 + nn];
    val = s;
  } else {
    float s = 0.f;
    for (int d = 0; d < 192; ++d)
      s += w2[((1 * 4 + nb) * 192 + kk) * 192 + d] * w2[((1 * 4 + nb) * 192 + d) * 192 + nn];
    val = w2[((0 * 4 + nb) * 192 + kk) * 192 + nn] - s;
  }
  w2t[((size_t)nb * 384 + n) * 384 + k] = f2bf(val);
  if (k == 0) {
    float bv;
    if (!nhi) {
      bv = b2[(0 * 4 + nb) * 192 + nn];
    } else {
      float s = 0.f;
      for (int d = 0; d < 192; ++d)
        s += b2[(0 * 4 + nb) * 192 + d] * w2[((1 * 4 + nb) * 192 + d) * 192 + nn];
      bv = b2[(1 * 4 + nb) * 192 + nn] + s;
    }
    bias2[nb * 384 + n] = bv;
  }
}

// ---------------- launcher ----------------
extern "C" void kernel_launch(void* const* d_in, const int* in_sizes, int n_in,
                              void* d_out, int out_size, void* d_ws, size_t ws_size,
                              hipStream_t stream) {
  (void)in_sizes; (void)n_in; (void)out_size; (void)ws_size;
  const float* x  = (const float*)d_in[0];
  const float* w1 = (const float*)d_in[1];
  const float* b1 = (const float*)d_in[2];
  const float* w2 = (const float*)d_in[3];
  const float* b2 = (const float*)d_in[4];
  const float* bw = (const float*)d_in[5];
  const float* bb = (const float*)d_in[6];
  float* out = (float*)d_out;

  // workspace (aliased lifetimes):
  //   buf1: Yw -> R1I1 -> G
  //   buf2: x_bf16 -> R2I2
  //   buf3: xf -> bias_bf16
  char* p = (char*)d_ws;
  unsigned short* buf1 = (unsigned short*)p; p += 51904512;
  unsigned short* buf2 = (unsigned short*)p; p += 51904512;
  unsigned short* buf3 = (unsigned short*)p; p += 51904512;
  unsigned short* bwb  = (unsigned short*)p; p += 1179648;
  unsigned short* w1t  = (unsigned short*)p; p += 1179648;
  unsigned short* w2t  = (unsigned short*)p; p += 1179648;
  float* bias1 = (float*)p; p += 6144;
  float* bias2 = (float*)p; p += 6144;

  // prep (small)
  cvt_bf16<<<589824 / 1024, 256, 0, stream>>>(bw, bwb);
  build_w1<<<589824 / 256, 256, 0, stream>>>(w1, b1, w1t, bias1);
  build_w2<<<589824 / 256, 256, 0, stream>>>(w2, b2, w2t, bias2);
  // forward FFT (pass A also emits x_bf16 into buf2)
  fft_fwd_w<<<dim3(BB * HH, 3), 256, 0, stream>>>(x, (ushort2*)buf1, buf2);
  fft_fwd_h<<<dim3(BB * W2C, 3), 256, 0, stream>>>((const ushort2*)buf1, buf3);
  // spectral layer 1 (consumes buf3=xf, frees it)
  gemm_bt<true, true><<<dim3(132, 3, 4), 256, 0, stream>>>(
      buf3, ROWW, 384, w1t, 384, 384 * 384, bias1, 384, buf1, ROWW, 384);
  // bias path GEMM -> bf16 into buf3 (M=32768, N=768, K=768)
  gemm_bt<false, true><<<dim3(256, 6, 1), 256, 0, stream>>>(
      buf2, 768, 0, bwb, 768, 0, bb, 0, buf3, 768, 0);
  // spectral layer 2
  gemm_bt<false, true><<<dim3(132, 3, 4), 256, 0, stream>>>(
      buf1, ROWW, 384, w2t, 384, 384 * 384, bias2, 384, buf2, ROWW, 384);
  // inverse FFT (+ bias, pure write of out)
  fft_inv_h<<<dim3(BB * W2C, 3), 256, 0, stream>>>(buf2, (ushort2*)buf1);
  fft_inv_w<<<dim3(BB * HH, 3), 256, 0, stream>>>((const ushort2*)buf1, buf3, out);
}

// Round 4
// 484.755 us; speedup vs baseline: 1.0797x; 1.0067x over previous
//
#include <hip/hip_runtime.h>
#include <hip/hip_bf16.h>
#include <stdint.h>

// Problem constants (fixed shapes)
#define BB 16
#define HH 32
#define WW 64
#define CC 768
#define W2C 33                   // WW/2+1
#define ROWW (2*CC)              // 1536 = NB*2*BS, spectral row layout (nb, re/im, bs)

typedef __bf16 bf16x8 __attribute__((ext_vector_type(8)));
typedef float f32x4 __attribute__((ext_vector_type(4)));

__device__ __forceinline__ unsigned short f2bf(float f) {
  __hip_bfloat16 h = __float2bfloat16(f);
  return __builtin_bit_cast(unsigned short, h);
}
__device__ __forceinline__ float bf2f(unsigned short u) {
  union { unsigned int i; float f; } x;
  x.i = ((unsigned int)u) << 16;
  return x.f;
}

// async global->LDS, 16B per lane
__device__ __forceinline__ void g2l16(const void* g, void* l) {
  __builtin_amdgcn_global_load_lds((const __attribute__((address_space(1))) unsigned int*)g,
                                   (__attribute__((address_space(3))) unsigned int*)l,
                                   16, 0, 0);
}

// compile-time bit reversal (folds after full unroll)
__device__ __host__ constexpr int brevc(int x, int bits) {
  int r = 0;
  for (int i = 0; i < bits; ++i) r |= ((x >> i) & 1) << (bits - 1 - i);
  return r;
}

// ---------------- radix-2 DIF FFT in registers (32-point) ----------------
template<int N, bool INV>
__device__ __forceinline__ void fft_reg(float2 (&v)[N], const float2* __restrict__ tw) {
  constexpr int LOG2N = (N == 64) ? 6 : 5;
#pragma unroll
  for (int s = 0; s < LOG2N; ++s) {
    const int len = N >> s;
    const int half = len >> 1;
    const int tstep = 64 / len;
#pragma unroll
    for (int i = 0; i < N; i += len) {
#pragma unroll
      for (int j = 0; j < half; ++j) {
        float2 u = v[i + j];
        float2 t = v[i + j + half];
        float sr = u.x + t.x, si = u.y + t.y;
        float dr = u.x - t.x, di = u.y - t.y;
        float2 w = tw[j * tstep];
        float wr = w.x;
        float wi = INV ? -w.y : w.y;
        v[i + j] = make_float2(sr, si);
        v[i + j + half] = make_float2(dr * wr - di * wi, dr * wi + di * wr);
      }
    }
  }
}

#define TW_INIT()                                                            \
  __shared__ float2 tw[64];                                                  \
  if (threadIdx.x < 64) {                                                    \
    float ang = (float)threadIdx.x * 0.09817477042468103f; /* 2pi/64 */      \
    tw[threadIdx.x] = make_float2(cosf(ang), -sinf(ang));                    \
  }                                                                          \
  __syncthreads();

// ---------------- forward pass A: rfft64 along W, LDS-staged wide loads ----------------
// Block: one (b,h) line x 256 channels. Stage x in two 32-row fp32 chunks (32 KB LDS),
// emit xb (bf16 x) from the same registers with ushort4 stores, z-pack from LDS,
// packed-real FFT in regs, strided yw stores (256 B/wave/instr).
__global__ __launch_bounds__(256) void fft_fwd_w(const float* __restrict__ x,
                                                 ushort2* __restrict__ yw,
                                                 unsigned short* __restrict__ xb) {
  __shared__ float2 tw[64];
  __shared__ __align__(16) float xs[32][256];
  const int t = threadIdx.x;
  if (t < 64) {
    float ang = (float)t * 0.09817477042468103f;
    tw[t] = make_float2(cosf(ang), -sinf(ang));
  }
  const int bh = blockIdx.x;
  const int c0 = blockIdx.y * 256;
  const float* xrow = x + (size_t)bh * (WW * CC) + c0;
  unsigned short* xbrow = xb + (size_t)bh * (WW * CC) + c0;
  const int rg = t >> 6;        // row group 0..3
  const int lc = (t & 63) * 4;  // float col within 256
  float2 v[32];
#pragma unroll
  for (int half = 0; half < 2; ++half) {
    __syncthreads();  // also covers tw init on first pass
#pragma unroll
    for (int it = 0; it < 8; ++it) {
      const int w = half * 32 + it * 4 + rg;
      float4 f = *(const float4*)(xrow + (size_t)w * CC + lc);
      *(float4*)&xs[it * 4 + rg][lc] = f;
      *(ushort4*)(xbrow + (size_t)w * CC + lc) =
          make_ushort4(f2bf(f.x), f2bf(f.y), f2bf(f.z), f2bf(f.w));
    }
    __syncthreads();
#pragma unroll
    for (int n = 0; n < 16; ++n)
      v[half * 16 + n] = make_float2(xs[2 * n][t], xs[2 * n + 1][t]);
  }
  fft_reg<32, false>(v, tw);
  ushort2* yp = yw + (size_t)bh * (W2C * CC) + c0 + t;
  {
    float2 Z0 = v[0];
    yp[0] = make_ushort2(f2bf(Z0.x + Z0.y), f2bf(0.f));
    yp[(size_t)32 * CC] = make_ushort2(f2bf(Z0.x - Z0.y), f2bf(0.f));
  }
#pragma unroll
  for (int k = 1; k < 32; ++k) {
    float2 Zk = v[brevc(k, 5)];
    float2 Zm = v[brevc(32 - k, 5)];
    float Er = 0.5f * (Zk.x + Zm.x), Ei = 0.5f * (Zk.y - Zm.y);
    float Odr = 0.5f * (Zk.y + Zm.y), Odi = -0.5f * (Zk.x - Zm.x);
    float2 w = tw[k];                       // W64^k = (cos, -sin)
    float Xr = Er + w.x * Odr - w.y * Odi;
    float Xi = Ei + w.x * Odi + w.y * Odr;
    yp[(size_t)k * CC] = make_ushort2(f2bf(Xr), f2bf(Xi));
  }
}

// ---------------- forward pass B: complex DFT along H (32), scale, write GEMM layout ---
__global__ __launch_bounds__(256) void fft_fwd_h(const ushort2* __restrict__ yw,
                                                 unsigned short* __restrict__ xf) {
  TW_INIT();
  const int bk = blockIdx.x;
  const int b = bk / W2C, kw = bk - b * W2C;
  const int c = blockIdx.y * 256 + threadIdx.x;
  const ushort2* yp = yw + ((size_t)b * HH * W2C + kw) * CC + c;
  float2 v[32];
#pragma unroll
  for (int h = 0; h < 32; ++h) {
    ushort2 u = yp[(size_t)h * (W2C * CC)];
    v[h] = make_float2(bf2f(u.x), bf2f(u.y));
  }
  fft_reg<32, false>(v, tw);
  const int nb = c / 192, cc = c - nb * 192;
  unsigned short* xp = xf + (size_t)nb * 384 + cc;
  const float s = 0.022097086912079608f; // 1/sqrt(2048)  (ortho fwd)
#pragma unroll
  for (int kh = 0; kh < 32; ++kh) {
    float2 z = v[brevc(kh, 5)];
    size_t m = ((size_t)b * HH + kh) * W2C + kw;
    xp[m * ROWW] = f2bf(z.x * s);
    xp[m * ROWW + 192] = f2bf(z.y * s);
  }
}

// ---------------- inverse pass A: complex inverse DFT along H ----------------
__global__ __launch_bounds__(256) void fft_inv_h(const unsigned short* __restrict__ r2,
                                                 ushort2* __restrict__ g) {
  TW_INIT();
  const int bk = blockIdx.x;
  const int b = bk / W2C, kw = bk - b * W2C;
  const int c = blockIdx.y * 256 + threadIdx.x;
  const int nb = c / 192, cc = c - nb * 192;
  const unsigned short* rp = r2 + (size_t)nb * 384 + cc;
  float2 v[32];
#pragma unroll
  for (int kh = 0; kh < 32; ++kh) {
    size_t m = ((size_t)b * HH + kh) * W2C + kw;
    v[kh] = make_float2(bf2f(rp[m * ROWW]), bf2f(rp[m * ROWW + 192]));
  }
  fft_reg<32, true>(v, tw);
  ushort2* gp = g + ((size_t)b * HH * W2C + kw) * CC + c;
#pragma unroll
  for (int h = 0; h < 32; ++h) {
    float2 z = v[brevc(h, 5)];
    gp[(size_t)h * (W2C * CC)] = make_ushort2(f2bf(z.x), f2bf(z.y));
  }
}

// ---------------- inverse pass B: irfft64 along W + bias, LDS-staged wide stores -------
// packed-real inverse (see R2); result goes to LDS fp32 in two 32-row chunks, then
// cooperative b128 LDS reads + ushort4 bias loads + dwordx4 out stores (1 KB/wave/instr).
__global__ __launch_bounds__(256) void fft_inv_w(const ushort2* __restrict__ g,
                                                 const unsigned short* __restrict__ biasb,
                                                 float* __restrict__ out) {
  __shared__ float2 tw[64];
  __shared__ __align__(16) float ys[32][256];
  const int t = threadIdx.x;
  if (t < 64) {
    float ang = (float)t * 0.09817477042468103f;
    tw[t] = make_float2(cosf(ang), -sinf(ang));
  }
  __syncthreads();
  const int bh = blockIdx.x;
  const int c0 = blockIdx.y * 256;
  const ushort2* gp = g + (size_t)bh * (W2C * CC) + c0 + t;
  float2 v[32];
  {
    float X0 = bf2f(gp[0].x);
    float X32 = bf2f(gp[(size_t)32 * CC].x);
    v[0] = make_float2(0.5f * (X0 + X32), 0.5f * (X0 - X32));
  }
#pragma unroll
  for (int k = 1; k < 32; ++k) {
    ushort2 uk = gp[(size_t)k * CC];
    ushort2 um = gp[(size_t)(32 - k) * CC];
    float2 Xk = make_float2(bf2f(uk.x), bf2f(uk.y));
    float2 Xm = make_float2(bf2f(um.x), bf2f(um.y));
    float Ar = 0.5f * (Xk.x + Xm.x), Ai = 0.5f * (Xk.y - Xm.y);
    float Dr = 0.5f * (Xk.x - Xm.x), Di = 0.5f * (Xk.y + Xm.y);
    float2 w = tw[k];                       // W64^{-k} = (w.x, -w.y)
    float Br = w.x * Dr + w.y * Di;
    float Bi = w.x * Di - w.y * Dr;
    v[k] = make_float2(Ar - Bi, Ai + Br);
  }
  fft_reg<32, true>(v, tw);
  const float s2 = 0.04419417382415922f; // 2/sqrt(2048)
  float* orow = out + (size_t)bh * (WW * CC) + c0;
  const unsigned short* brow = biasb + (size_t)bh * (WW * CC) + c0;
  const int rg = t >> 6;
  const int lc = (t & 63) * 4;
#pragma unroll
  for (int half = 0; half < 2; ++half) {
    __syncthreads();
#pragma unroll
    for (int n = 0; n < 16; ++n) {
      float2 z = v[brevc(half * 16 + n, 5)];
      ys[2 * n][t] = z.x * s2;
      ys[2 * n + 1][t] = z.y * s2;
    }
    __syncthreads();
#pragma unroll
    for (int it = 0; it < 8; ++it) {
      const int w = half * 32 + it * 4 + rg;
      float4 f = *(const float4*)&ys[it * 4 + rg][lc];
      ushort4 b4 = *(const ushort4*)(brow + (size_t)w * CC + lc);
      f.x += bf2f(b4.x); f.y += bf2f(b4.y); f.z += bf2f(b4.z); f.w += bf2f(b4.w);
      *(float4*)(orow + (size_t)w * CC + lc) = f;
    }
  }
}

// ---------------- bf16 MFMA GEMM (m97 structure + XOR bank swizzle) ----------------
template<bool RELU, bool OBF>
__global__ __launch_bounds__(256) void gemm_bt(
    const unsigned short* __restrict__ A, int lda, int aZ,
    const unsigned short* __restrict__ Bw, int K, int bZ,
    const float* __restrict__ bias, int biasZ,
    void* __restrict__ outp, int ldo, int oZ) {
  __shared__ __align__(16) unsigned short As[128 * 32];
  __shared__ __align__(16) unsigned short Bs[128 * 32];
  const int t = threadIdx.x;
  const int z = blockIdx.z;
  const size_t m0 = (size_t)blockIdx.x * 128;
  const int n0 = blockIdx.y * 128;
  const unsigned short* Ap = A + m0 * lda + (size_t)z * aZ;
  const unsigned short* Bp = Bw + (size_t)n0 * K + (size_t)z * bZ;
  const int lane = t & 63, wave = t >> 6;
  const int lr = lane & 15, quad = lane >> 4;
  const int wm = (wave >> 1) * 64, wn = (wave & 1) * 64;
  const int row = t >> 2;                     // 0..63
  const int sl = t & 3;                       // 16B slot within row
  const int kb = (sl ^ ((row >> 1) & 3)) * 8; // swizzled global k-chunk
  const int swzf = (lr >> 1) & 3;             // fragment-read swizzle
  f32x4 acc[4][4] = {};
  for (int k0 = 0; k0 < K; k0 += 32) {
    const unsigned short* ga = Ap + (size_t)row * lda + (k0 + kb);
    g2l16(ga, &As[row * 32 + sl * 8]);
    g2l16(ga + (size_t)64 * lda, &As[(row + 64) * 32 + sl * 8]);
    const unsigned short* gb = Bp + (size_t)row * K + (k0 + kb);
    g2l16(gb, &Bs[row * 32 + sl * 8]);
    g2l16(gb + (size_t)64 * K, &Bs[(row + 64) * 32 + sl * 8]);
    __syncthreads();
    bf16x8 af[4], bfr[4];
#pragma unroll
    for (int mi = 0; mi < 4; ++mi)
      af[mi] = *(const bf16x8*)&As[(wm + mi * 16 + lr) * 32 + ((quad ^ swzf) * 8)];
#pragma unroll
    for (int ni = 0; ni < 4; ++ni)
      bfr[ni] = *(const bf16x8*)&Bs[(wn + ni * 16 + lr) * 32 + ((quad ^ swzf) * 8)];
#pragma unroll
    for (int mi = 0; mi < 4; ++mi)
#pragma unroll
      for (int ni = 0; ni < 4; ++ni)
        acc[mi][ni] = __builtin_amdgcn_mfma_f32_16x16x32_bf16(af[mi], bfr[ni], acc[mi][ni], 0, 0, 0);
    __syncthreads();
  }
#pragma unroll
  for (int mi = 0; mi < 4; ++mi) {
    const size_t mrow = m0 + wm + mi * 16 + quad * 4;
#pragma unroll
    for (int ni = 0; ni < 4; ++ni) {
      const int ncol = n0 + wn + ni * 16 + lr;
      const float bv = bias[z * biasZ + ncol];
#pragma unroll
      for (int r = 0; r < 4; ++r) {
        float vv = acc[mi][ni][r] + bv;
        if (RELU) vv = fmaxf(vv, 0.f);
        const size_t off = (mrow + r) * (size_t)ldo + (size_t)z * oZ + ncol;
        if (OBF) ((unsigned short*)outp)[off] = f2bf(vv);
        else ((float*)outp)[off] = vv;
      }
    }
  }
}

// ---------------- prep kernels ----------------
__global__ __launch_bounds__(256) void cvt_bf16(const float* __restrict__ in,
                                                unsigned short* __restrict__ outp) {
  const size_t i = ((size_t)blockIdx.x * 256 + threadIdx.x) * 4;
  float4 v = *(const float4*)(in + i);
  ushort4 o = make_ushort4(f2bf(v.x), f2bf(v.y), f2bf(v.z), f2bf(v.w));
  *(ushort4*)(outp + i) = o;
}

// Combined layer-1 weights, stored n-major (nb, n, k), k,n in [0,384)
__global__ __launch_bounds__(256) void build_w1(const float* __restrict__ w1,
                                                const float* __restrict__ b1,
                                                unsigned short* __restrict__ w1t,
                                                float* __restrict__ bias1) {
  const int idx = blockIdx.x * 256 + threadIdx.x;
  const int nb = idx / (384 * 384);
  const int rem = idx - nb * (384 * 384);
  const int n = rem / 384, k = rem - (rem / 384) * 384;
  const bool khi = k >= 192, nhi = n >= 192;
  const int kk = khi ? k - 192 : k, nn = nhi ? n - 192 : n;
  float val;
  if (!khi && !nhi)      val =  w1[((0 * 4 + nb) * 192 + kk) * 192 + nn];
  else if (khi && !nhi)  val = -w1[((1 * 4 + nb) * 192 + kk) * 192 + nn];
  else if (!khi && nhi)  val =  w1[((1 * 4 + nb) * 192 + kk) * 192 + nn];
  else                   val =  w1[((0 * 4 + nb) * 192 + kk) * 192 + nn];
  w1t[((size_t)nb * 384 + n) * 384 + k] = f2bf(val);
  if (k == 0)
    bias1[nb * 384 + n] = nhi ? b1[(1 * 4 + nb) * 192 + nn] : b1[(0 * 4 + nb) * 192 + nn];
}

// Combined layer-2 weights (folds the in-place r2->i2 dependency).
__global__ __launch_bounds__(256) void build_w2(const float* __restrict__ w2,
                                                const float* __restrict__ b2,
                                                unsigned short* __restrict__ w2t,
                                                float* __restrict__ bias2) {
  const int idx = blockIdx.x * 256 + threadIdx.x;
  const int nb = idx / (384 * 384);
  const int rem = idx - nb * (384 * 384);
  const int n = rem / 384, k = rem - (rem / 384) * 384;
  const bool khi = k >= 192, nhi = n >= 192;
  const int kk = khi ? k - 192 : k, nn = nhi ? n - 192 : n;
  float val;
  if (!khi && !nhi) {
    val = w2[((0 * 4 + nb) * 192 + kk) * 192 + nn];
  } else if (khi && !nhi) {
    val = -w2[((1 * 4 + nb) * 192 + kk) * 192 + nn];
  } else if (!khi && nhi) {
    float s = 0.f;
    for (int d = 0; d < 192; ++d)
      s += w2[((0 * 4 + nb) * 192 + kk) * 192 + d] * w2[((1 * 4 + nb) * 192 + d) * 192 + nn];
    val = s;
  } else {
    float s = 0.f;
    for (int d = 0; d < 192; ++d)
      s += w2[((1 * 4 + nb) * 192 + kk) * 192 + d] * w2[((1 * 4 + nb) * 192 + d) * 192 + nn];
    val = w2[((0 * 4 + nb) * 192 + kk) * 192 + nn] - s;
  }
  w2t[((size_t)nb * 384 + n) * 384 + k] = f2bf(val);
  if (k == 0) {
    float bv;
    if (!nhi) {
      bv = b2[(0 * 4 + nb) * 192 + nn];
    } else {
      float s = 0.f;
      for (int d = 0; d < 192; ++d)
        s += b2[(0 * 4 + nb) * 192 + d] * w2[((1 * 4 + nb) * 192 + d) * 192 + nn];
      bv = b2[(1 * 4 + nb) * 192 + nn] + s;
    }
    bias2[nb * 384 + n] = bv;
  }
}

// ---------------- launcher ----------------
extern "C" void kernel_launch(void* const* d_in, const int* in_sizes, int n_in,
                              void* d_out, int out_size, void* d_ws, size_t ws_size,
                              hipStream_t stream) {
  (void)in_sizes; (void)n_in; (void)out_size; (void)ws_size;
  const float* x  = (const float*)d_in[0];
  const float* w1 = (const float*)d_in[1];
  const float* b1 = (const float*)d_in[2];
  const float* w2 = (const float*)d_in[3];
  const float* b2 = (const float*)d_in[4];
  const float* bw = (const float*)d_in[5];
  const float* bb = (const float*)d_in[6];
  float* out = (float*)d_out;

  // workspace (aliased lifetimes):
  //   buf1: Yw -> R1I1 -> G
  //   buf2: x_bf16 -> R2I2
  //   buf3: xf -> bias_bf16
  char* p = (char*)d_ws;
  unsigned short* buf1 = (unsigned short*)p; p += 51904512;
  unsigned short* buf2 = (unsigned short*)p; p += 51904512;
  unsigned short* buf3 = (unsigned short*)p; p += 51904512;
  unsigned short* bwb  = (unsigned short*)p; p += 1179648;
  unsigned short* w1t  = (unsigned short*)p; p += 1179648;
  unsigned short* w2t  = (unsigned short*)p; p += 1179648;
  float* bias1 = (float*)p; p += 6144;
  float* bias2 = (float*)p; p += 6144;

  // prep (small)
  cvt_bf16<<<589824 / 1024, 256, 0, stream>>>(bw, bwb);
  build_w1<<<589824 / 256, 256, 0, stream>>>(w1, b1, w1t, bias1);
  build_w2<<<589824 / 256, 256, 0, stream>>>(w2, b2, w2t, bias2);
  // forward FFT (pass A also emits x_bf16 into buf2)
  fft_fwd_w<<<dim3(BB * HH, 3), 256, 0, stream>>>(x, (ushort2*)buf1, buf2);
  fft_fwd_h<<<dim3(BB * W2C, 3), 256, 0, stream>>>((const ushort2*)buf1, buf3);
  // spectral layer 1 (consumes buf3=xf, frees it)
  gemm_bt<true, true><<<dim3(132, 3, 4), 256, 0, stream>>>(
      buf3, ROWW, 384, w1t, 384, 384 * 384, bias1, 384, buf1, ROWW, 384);
  // bias path GEMM -> bf16 into buf3 (M=32768, N=768, K=768)
  gemm_bt<false, true><<<dim3(256, 6, 1), 256, 0, stream>>>(
      buf2, 768, 0, bwb, 768, 0, bb, 0, buf3, 768, 0);
  // spectral layer 2
  gemm_bt<false, true><<<dim3(132, 3, 4), 256, 0, stream>>>(
      buf1, ROWW, 384, w2t, 384, 384 * 384, bias2, 384, buf2, ROWW, 384);
  // inverse FFT (+ bias, pure write of out)
  fft_inv_h<<<dim3(BB * W2C, 3), 256, 0, stream>>>(buf2, (ushort2*)buf1);
  fft_inv_w<<<dim3(BB * HH, 3), 256, 0, stream>>>((const ushort2*)buf1, buf3, out);
}